// Round 2
// baseline (1262.240 us; speedup 1.0000x reference)
//
#include <hip/hip_runtime.h>
#include <hip/hip_bf16.h>

typedef unsigned short u16;
typedef short bf16x8 __attribute__((ext_vector_type(8)));    // 8 bf16 = 4 VGPRs
typedef float floatx4 __attribute__((ext_vector_type(4)));
typedef unsigned short u16x4 __attribute__((ext_vector_type(4)));
typedef unsigned short u16x8 __attribute__((ext_vector_type(8)));

__device__ __forceinline__ u16 f2bf(float f) {
    unsigned int x; __builtin_memcpy(&x, &f, 4);
    unsigned int r = x + 0x7fffu + ((x >> 16) & 1u);   // RNE
    return (u16)(r >> 16);
}
__device__ __forceinline__ float sigm(float x) {
    return 1.f / (1.f + __expf(-x));
}
__device__ __forceinline__ float tanhx(float x) {
    x = fminf(fmaxf(x, -15.f), 15.f);
    float e = __expf(2.f * x);
    return (e - 1.f) / (e + 1.f);
}

// async 16B global->LDS (global_load_lds_dwordx4). LDS dest is wave-uniform
// base + lane*16 -> thread t must map to LDS chunk t (m97 pattern, no padding).
__device__ __forceinline__ void async16(const void* g, void* l) {
    __builtin_amdgcn_global_load_lds(
        (__attribute__((address_space(1))) void*)(void*)(g),
        (__attribute__((address_space(3))) void*)(l),
        16, 0, 0);
}

// ------------- transpose + convert: in (K,N) f32 row-major -> out (N,K) bf16 -------------
__global__ __launch_bounds__(256) void transpose_f32_bf16(
    const float* __restrict__ in, u16* __restrict__ out, int K, int N)
{
    __shared__ float tile[64][65];
    const int n0 = blockIdx.x * 64, k0 = blockIdx.y * 64;
    const int t = threadIdx.x;
    const int tc = t & 15, tr = t >> 4;
#pragma unroll
    for (int i = 0; i < 4; i++) {
        int k = i * 16 + tr;
        int n = tc * 4;
        float4 v = *(const float4*)&in[(size_t)(k0 + k) * N + n0 + n];
        tile[k][n + 0] = v.x; tile[k][n + 1] = v.y;
        tile[k][n + 2] = v.z; tile[k][n + 3] = v.w;
    }
    __syncthreads();
#pragma unroll
    for (int i = 0; i < 4; i++) {
        int n = i * 16 + tr;
        int k = tc * 4;
        u16x4 v;
        v.x = f2bf(tile[k + 0][n]);
        v.y = f2bf(tile[k + 1][n]);
        v.z = f2bf(tile[k + 2][n]);
        v.w = f2bf(tile[k + 3][n]);
        *(u16x4*)&out[(size_t)(n0 + n) * K + k0 + k] = v;
    }
}

// ------ gather + convert: X[t][b] = [emb[path[b][1+2t]], emb[path[b][2+2t]]] f32->bf16 ------
__global__ __launch_bounds__(256) void gather_x(
    const int* __restrict__ path, const float* __restrict__ emb, u16* __restrict__ X)
{
    const int blk = blockIdx.x;          // t*1024 + b
    const int t = blk >> 10, b = blk & 1023;
    const int tt = threadIdx.x;
    const int half = tt >> 7;            // 0: prev idx (odd pos), 1: curr idx (even pos)
    const int idx = path[b * 11 + 1 + 2 * t + half];
    const int j = (tt & 127) * 8;
    const float4 v0 = *(const float4*)&emb[(size_t)idx * 1024 + j];
    const float4 v1 = *(const float4*)&emb[(size_t)idx * 1024 + j + 4];
    u16x8 o;
    o[0] = f2bf(v0.x); o[1] = f2bf(v0.y); o[2] = f2bf(v0.z); o[3] = f2bf(v0.w);
    o[4] = f2bf(v1.x); o[5] = f2bf(v1.y); o[6] = f2bf(v1.z); o[7] = f2bf(v1.w);
    *(u16x8*)&X[(size_t)blk * 2048 + half * 1024 + j] = o;
}

// ---------------- GEMM: C(MxN) = A(MxK) * Bt(NxK)^T, bf16 in, f32 acc ----------------
// MODE 0: Cf = A*B + bias          (f32 out)
// MODE 1: Cf += A*B                (f32 in/out)
// MODE 2: Cb = relu(A*B + bias)    (bf16 out)
template <int MODE>
__global__ __launch_bounds__(256, 2) void gemm_bt(
    const u16* __restrict__ A, const u16* __restrict__ Bt,
    const float* __restrict__ bias, float* __restrict__ Cf, u16* __restrict__ Cb,
    int M, int N, int K)
{
    __shared__ alignas(16) u16 sA[128 * 32];
    __shared__ alignas(16) u16 sB[128 * 32];

    const int t = threadIdx.x;
    const int lane = t & 63;
    const int w = t >> 6;
    const int wr = w >> 1, wc = w & 1;       // 2x2 wave grid, each wave 64x64
    const int l15 = lane & 15, quad = lane >> 4;
    const int m0 = blockIdx.x * 128, n0 = blockIdx.y * 128;

    // staging: 512 chunks of 16B per tile; thread t -> chunks t and t+256
    const int ch1 = t, ch2 = t + 256;
    const int r1 = ch1 >> 2, c1 = (ch1 & 3) * 8;
    const int r2 = ch2 >> 2, c2 = (ch2 & 3) * 8;

    floatx4 acc[4][4] = {};

    for (int k0 = 0; k0 < K; k0 += 32) {
        async16(A + (size_t)(m0 + r1) * K + k0 + c1, sA + ch1 * 8);
        async16(A + (size_t)(m0 + r2) * K + k0 + c2, sA + ch2 * 8);
        async16(Bt + (size_t)(n0 + r1) * K + k0 + c1, sB + ch1 * 8);
        async16(Bt + (size_t)(n0 + r2) * K + k0 + c2, sB + ch2 * 8);
        __syncthreads();

        bf16x8 af[4], bfr[4];
#pragma unroll
        for (int mi = 0; mi < 4; mi++)
            af[mi] = *(const bf16x8*)&sA[(wr * 64 + mi * 16 + l15) * 32 + quad * 8];
#pragma unroll
        for (int ni = 0; ni < 4; ni++)
            bfr[ni] = *(const bf16x8*)&sB[(wc * 64 + ni * 16 + l15) * 32 + quad * 8];
#pragma unroll
        for (int mi = 0; mi < 4; mi++)
#pragma unroll
            for (int ni = 0; ni < 4; ni++)
                acc[mi][ni] = __builtin_amdgcn_mfma_f32_16x16x32_bf16(
                    af[mi], bfr[ni], acc[mi][ni], 0, 0, 0);
        __syncthreads();
    }

#pragma unroll
    for (int mi = 0; mi < 4; mi++) {
#pragma unroll
        for (int ni = 0; ni < 4; ni++) {
            const int n = n0 + wc * 64 + ni * 16 + l15;
            float bv = 0.f;
            if (MODE != 1) bv = bias[n];
#pragma unroll
            for (int r = 0; r < 4; r++) {
                const int m = m0 + wr * 64 + mi * 16 + quad * 4 + r;
                float v = acc[mi][ni][r];
                if (MODE == 0) {
                    Cf[(size_t)m * N + n] = v + bv;
                } else if (MODE == 1) {
                    Cf[(size_t)m * N + n] += v;
                } else {
                    float x = v + bv;
                    x = x > 0.f ? x : 0.f;
                    Cb[(size_t)m * N + n] = f2bf(x);
                }
            }
        }
    }
}

// ---------------- LSTM gates: z(1024x8192 f32) -> c (f32), h (bf16) ----------------
template <bool FIRST>
__global__ __launch_bounds__(256) void lstm_gate(
    const float* __restrict__ Z, float* __restrict__ c, u16* __restrict__ h)
{
    const int idx = blockIdx.x * 256 + threadIdx.x;   // 0 .. 1024*512-1
    const int b = idx >> 9;
    const int j = (idx & 511) * 4;
    const size_t zb = (size_t)b * 8192 + j;
    const float4 vi = *(const float4*)&Z[zb];
    const float4 vf = *(const float4*)&Z[zb + 2048];
    const float4 vg = *(const float4*)&Z[zb + 4096];
    const float4 vo = *(const float4*)&Z[zb + 6144];
    const size_t cb = (size_t)b * 2048 + j;
    float4 vc;
    if (FIRST) vc = make_float4(0.f, 0.f, 0.f, 0.f);
    else       vc = *(const float4*)&c[cb];

    float ia[4] = {vi.x, vi.y, vi.z, vi.w};
    float fa[4] = {vf.x, vf.y, vf.z, vf.w};
    float ga[4] = {vg.x, vg.y, vg.z, vg.w};
    float oa[4] = {vo.x, vo.y, vo.z, vo.w};
    float ca[4] = {vc.x, vc.y, vc.z, vc.w};
    float cn[4]; u16x4 hv;
#pragma unroll
    for (int q = 0; q < 4; q++) {
        float i_ = sigm(ia[q]);
        float f_ = sigm(fa[q]);
        float g_ = tanhx(ga[q]);
        float o_ = sigm(oa[q]);
        cn[q] = f_ * ca[q] + i_ * g_;
        float h_ = o_ * tanhx(cn[q]);
        ((u16*)&hv)[q] = f2bf(h_);
    }
    *(float4*)&c[cb] = make_float4(cn[0], cn[1], cn[2], cn[3]);
    *(u16x4*)&h[cb] = hv;
}

// ---------------- head: logits = a2 @ W3 + b3 (f32), softmax over 2, f32 out ----------------
__global__ __launch_bounds__(256) void head_kernel(
    const u16* __restrict__ a2, const float* __restrict__ W3,
    const float* __restrict__ b3, float* __restrict__ out)
{
    const int t = threadIdx.x;
    const int w = t >> 6, lane = t & 63;
    const int b = blockIdx.x * 4 + w;     // 256 blocks * 4 waves = 1024 rows
    float s0 = 0.f, s1 = 0.f;
    for (int k = lane; k < 2048; k += 64) {
        unsigned int u = ((unsigned int)a2[(size_t)b * 2048 + k]) << 16;
        float a; __builtin_memcpy(&a, &u, 4);
        s0 += a * W3[2 * k];
        s1 += a * W3[2 * k + 1];
    }
#pragma unroll
    for (int off = 32; off > 0; off >>= 1) {
        s0 += __shfl_down(s0, off);
        s1 += __shfl_down(s1, off);
    }
    if (lane == 0) {
        float l0 = s0 + b3[0];
        float l1 = s1 + b3[1];
        float m = fmaxf(l0, l1);
        float e0 = __expf(l0 - m), e1 = __expf(l1 - m);
        float inv = 1.f / (e0 + e1);
        out[2 * b]     = e0 * inv;
        out[2 * b + 1] = e1 * inv;
    }
}

extern "C" void kernel_launch(void* const* d_in, const int* in_sizes, int n_in,
                              void* d_out, int out_size, void* d_ws, size_t ws_size,
                              hipStream_t stream) {
    const int*   path = (const int*)d_in[0];
    const float* emb  = (const float*)d_in[1];
    const float* W    = (const float*)d_in[2];
    const float* U    = (const float*)d_in[3];
    const float* bl   = (const float*)d_in[4];
    const float* W1   = (const float*)d_in[5];
    const float* b1   = (const float*)d_in[6];
    const float* W2   = (const float*)d_in[7];
    const float* b2   = (const float*)d_in[8];
    const float* W3   = (const float*)d_in[9];
    const float* b3   = (const float*)d_in[10];

    // workspace layout (bytes)
    const size_t NEED = 159383552;
    if (ws_size < NEED) return;   // diagnostic: absmax would equal stub value 0.59375
    char* ws = (char*)d_ws;
    u16*  Wt  = (u16*) (ws + 0);          // 8192x2048 bf16  (33554432 B)
    u16*  Ut  = (u16*) (ws + 33554432);   // 8192x2048 bf16
    u16*  W1t = (u16*) (ws + 67108864);   // 2048x2048 bf16  (8388608 B)
    u16*  W2t = (u16*) (ws + 75497472);   // 2048x2048 bf16
    u16*  X   = (u16*) (ws + 83886080);   // 5x1024x2048 bf16 (20971520 B)
    float* Z  = (float*)(ws + 104857600); // 1024x8192 f32   (33554432 B)
    float* c  = (float*)(ws + 138412032); // 1024x2048 f32   (8388608 B)
    u16*  h   = (u16*) (ws + 146800640);  // 1024x2048 bf16
    u16*  a1  = (u16*) (ws + 150994944);  // 1024x2048 bf16
    u16*  a2  = (u16*) (ws + 155189248);  // 1024x2048 bf16

    transpose_f32_bf16<<<dim3(128, 32), 256, 0, stream>>>(W, Wt, 2048, 8192);
    transpose_f32_bf16<<<dim3(128, 32), 256, 0, stream>>>(U, Ut, 2048, 8192);
    transpose_f32_bf16<<<dim3(32, 32), 256, 0, stream>>>(W1, W1t, 2048, 2048);
    transpose_f32_bf16<<<dim3(32, 32), 256, 0, stream>>>(W2, W2t, 2048, 2048);
    gather_x<<<5120, 256, 0, stream>>>(path, emb, X);

    for (int t = 0; t < 5; t++) {
        gemm_bt<0><<<dim3(8, 64), 256, 0, stream>>>(
            X + (size_t)t * 1024 * 2048, Wt, bl, Z, nullptr, 1024, 8192, 2048);
        if (t > 0)
            gemm_bt<1><<<dim3(8, 64), 256, 0, stream>>>(
                h, Ut, nullptr, Z, nullptr, 1024, 8192, 2048);
        if (t == 0) lstm_gate<true ><<<2048, 256, 0, stream>>>(Z, c, h);
        else        lstm_gate<false><<<2048, 256, 0, stream>>>(Z, c, h);
    }

    gemm_bt<2><<<dim3(8, 16), 256, 0, stream>>>(h,  W1t, b1, nullptr, a1, 1024, 2048, 2048);
    gemm_bt<2><<<dim3(8, 16), 256, 0, stream>>>(a1, W2t, b2, nullptr, a2, 1024, 2048, 2048);
    head_kernel<<<256, 256, 0, stream>>>(a2, W3, b3, (float*)d_out);
}

// Round 3
// 1129.791 us; speedup vs baseline: 1.1172x; 1.1172x over previous
//
#include <hip/hip_runtime.h>
#include <hip/hip_bf16.h>

typedef unsigned short u16;
typedef short bf16x8 __attribute__((ext_vector_type(8)));    // 8 bf16 = 4 VGPRs
typedef float floatx4 __attribute__((ext_vector_type(4)));
typedef unsigned short u16x4 __attribute__((ext_vector_type(4)));
typedef unsigned short u16x8 __attribute__((ext_vector_type(8)));

__device__ __forceinline__ u16 f2bf(float f) {
    unsigned int x; __builtin_memcpy(&x, &f, 4);
    unsigned int r = x + 0x7fffu + ((x >> 16) & 1u);   // RNE
    return (u16)(r >> 16);
}
__device__ __forceinline__ float sigm(float x) {
    return 1.f / (1.f + __expf(-x));
}
__device__ __forceinline__ float tanhx(float x) {
    x = fminf(fmaxf(x, -15.f), 15.f);
    float e = __expf(2.f * x);
    return (e - 1.f) / (e + 1.f);
}

// column permutation: original col c = gate*2048 + j (j = j_hi*16 + j_lo)
//   -> permuted c' = j_hi*64 + gate*16 + j_lo
// so each 64-col group holds {i,f,g,o}x16 for 16 consecutive j -> in the
// 128x128 GEMM tile, ni (16-col subtile index within a wave's 64 cols)
// IS the gate index and no cross-lane exchange is needed in the epilogue.
__device__ __forceinline__ int permc(int c) {
    int gate = c >> 11, j = c & 2047;
    return ((j >> 4) << 6) | (gate << 4) | (j & 15);
}

// async 16B global->LDS (global_load_lds_dwordx4). LDS dest is wave-uniform
// base + lane*16 -> thread t must map to LDS chunk t (m97 pattern, no padding).
__device__ __forceinline__ void async16(const void* g, void* l) {
    __builtin_amdgcn_global_load_lds(
        (__attribute__((address_space(1))) void*)(void*)(g),
        (__attribute__((address_space(3))) void*)(l),
        16, 0, 0);
}

// ------------- transpose + convert: in (K,N) f32 -> out (N,K) bf16, opt col-perm -------------
template <bool PERM>
__global__ __launch_bounds__(256) void transpose_f32_bf16(
    const float* __restrict__ in, u16* __restrict__ out, int K, int N)
{
    __shared__ float tile[64][65];
    const int n0 = blockIdx.x * 64, k0 = blockIdx.y * 64;
    const int t = threadIdx.x;
    const int tc = t & 15, tr = t >> 4;
#pragma unroll
    for (int i = 0; i < 4; i++) {
        int k = i * 16 + tr;
        int n = tc * 4;
        float4 v = *(const float4*)&in[(size_t)(k0 + k) * N + n0 + n];
        tile[k][n + 0] = v.x; tile[k][n + 1] = v.y;
        tile[k][n + 2] = v.z; tile[k][n + 3] = v.w;
    }
    __syncthreads();
#pragma unroll
    for (int i = 0; i < 4; i++) {
        int n = i * 16 + tr;
        int k = tc * 4;
        u16x4 v;
        v.x = f2bf(tile[k + 0][n]);
        v.y = f2bf(tile[k + 1][n]);
        v.z = f2bf(tile[k + 2][n]);
        v.w = f2bf(tile[k + 3][n]);
        const int row = PERM ? permc(n0 + n) : (n0 + n);
        *(u16x4*)&out[(size_t)row * K + k0 + k] = v;
    }
}

// ------ gather + convert: X[t][b] = [emb[path[b][1+2t]], emb[path[b][2+2t]]] f32->bf16 ------
__global__ __launch_bounds__(256) void gather_x(
    const int* __restrict__ path, const float* __restrict__ emb, u16* __restrict__ X)
{
    const int blk = blockIdx.x;          // t*1024 + b
    const int t = blk >> 10, b = blk & 1023;
    const int tt = threadIdx.x;
    const int half = tt >> 7;
    const int idx = path[b * 11 + 1 + 2 * t + half];
    const int j = (tt & 127) * 8;
    const float4 v0 = *(const float4*)&emb[(size_t)idx * 1024 + j];
    const float4 v1 = *(const float4*)&emb[(size_t)idx * 1024 + j + 4];
    u16x8 o;
    o[0] = f2bf(v0.x); o[1] = f2bf(v0.y); o[2] = f2bf(v0.z); o[3] = f2bf(v0.w);
    o[4] = f2bf(v1.x); o[5] = f2bf(v1.y); o[6] = f2bf(v1.z); o[7] = f2bf(v1.w);
    *(u16x8*)&X[(size_t)blk * 2048 + half * 1024 + j] = o;
}

// ---- batched Zx GEMM: Zx(5120x8192) = X(5120x2048) @ Wt'(8192x2048)^T + b (perm cols) ----
__global__ __launch_bounds__(256, 2) void gemm_zx(
    const u16* __restrict__ A, const u16* __restrict__ Bt,
    const float* __restrict__ bias, float* __restrict__ Cf, int M, int N, int K)
{
    __shared__ alignas(16) u16 sA[128 * 32];
    __shared__ alignas(16) u16 sB[128 * 32];
    const int t = threadIdx.x;
    const int lane = t & 63;
    const int w = t >> 6;
    const int wr = w >> 1, wc = w & 1;
    const int l15 = lane & 15, quad = lane >> 4;
    const int m0 = blockIdx.x * 128, n0 = blockIdx.y * 128;
    const int ch1 = t, ch2 = t + 256;
    const int r1 = ch1 >> 2, c1 = (ch1 & 3) * 8;
    const int r2 = ch2 >> 2, c2 = (ch2 & 3) * 8;

    floatx4 acc[4][4] = {};
    for (int k0 = 0; k0 < K; k0 += 32) {
        async16(A + (size_t)(m0 + r1) * K + k0 + c1, sA + ch1 * 8);
        async16(A + (size_t)(m0 + r2) * K + k0 + c2, sA + ch2 * 8);
        async16(Bt + (size_t)(n0 + r1) * K + k0 + c1, sB + ch1 * 8);
        async16(Bt + (size_t)(n0 + r2) * K + k0 + c2, sB + ch2 * 8);
        __syncthreads();
        bf16x8 af[4], bfr[4];
#pragma unroll
        for (int mi = 0; mi < 4; mi++)
            af[mi] = *(const bf16x8*)&sA[(wr * 64 + mi * 16 + l15) * 32 + quad * 8];
#pragma unroll
        for (int ni = 0; ni < 4; ni++)
            bfr[ni] = *(const bf16x8*)&sB[(wc * 64 + ni * 16 + l15) * 32 + quad * 8];
#pragma unroll
        for (int mi = 0; mi < 4; mi++)
#pragma unroll
            for (int ni = 0; ni < 4; ni++)
                acc[mi][ni] = __builtin_amdgcn_mfma_f32_16x16x32_bf16(
                    af[mi], bfr[ni], acc[mi][ni], 0, 0, 0);
        __syncthreads();
    }
#pragma unroll
    for (int mi = 0; mi < 4; mi++) {
#pragma unroll
        for (int ni = 0; ni < 4; ni++) {
            const int n = n0 + wc * 64 + ni * 16 + l15;   // permuted col
            // inverse perm: gate=(n>>4)&3, j = ((n>>6)<<4)|(n&15)
            const float bv = bias[(((n >> 4) & 3) << 11) | ((n >> 6) << 4) | (n & 15)];
#pragma unroll
            for (int r = 0; r < 4; r++) {
                const int m = m0 + wr * 64 + mi * 16 + quad * 4 + r;
                Cf[(size_t)m * N + n] = acc[mi][ni][r] + bv;
            }
        }
    }
}

// ---- fused step: z = Zx_t + h@Ut'(perm); gates in epilogue -> c (f32), hout (bf16) ----
__global__ __launch_bounds__(256, 2) void gemm_step(
    const u16* __restrict__ hin, const u16* __restrict__ Bt,
    const float* __restrict__ Zx, float* __restrict__ c, u16* __restrict__ hout)
{
    const int M = 1024, N = 8192, K = 2048;
    __shared__ alignas(16) u16 sA[128 * 32];
    __shared__ alignas(16) u16 sB[128 * 32];
    const int t = threadIdx.x;
    const int lane = t & 63;
    const int w = t >> 6;
    const int wr = w >> 1, wc = w & 1;
    const int l15 = lane & 15, quad = lane >> 4;
    const int m0 = blockIdx.x * 128, n0 = blockIdx.y * 128;
    const int ch1 = t, ch2 = t + 256;
    const int r1 = ch1 >> 2, c1 = (ch1 & 3) * 8;
    const int r2 = ch2 >> 2, c2 = (ch2 & 3) * 8;

    floatx4 acc[4][4] = {};
    for (int k0 = 0; k0 < K; k0 += 32) {
        async16(hin + (size_t)(m0 + r1) * K + k0 + c1, sA + ch1 * 8);
        async16(hin + (size_t)(m0 + r2) * K + k0 + c2, sA + ch2 * 8);
        async16(Bt + (size_t)(n0 + r1) * K + k0 + c1, sB + ch1 * 8);
        async16(Bt + (size_t)(n0 + r2) * K + k0 + c2, sB + ch2 * 8);
        __syncthreads();
        bf16x8 af[4], bfr[4];
#pragma unroll
        for (int mi = 0; mi < 4; mi++)
            af[mi] = *(const bf16x8*)&sA[(wr * 64 + mi * 16 + l15) * 32 + quad * 8];
#pragma unroll
        for (int ni = 0; ni < 4; ni++)
            bfr[ni] = *(const bf16x8*)&sB[(wc * 64 + ni * 16 + l15) * 32 + quad * 8];
#pragma unroll
        for (int mi = 0; mi < 4; mi++)
#pragma unroll
            for (int ni = 0; ni < 4; ni++)
                acc[mi][ni] = __builtin_amdgcn_mfma_f32_16x16x32_bf16(
                    af[mi], bfr[ni], acc[mi][ni], 0, 0, 0);
        __syncthreads();
    }

    // epilogue: ni = gate index (thanks to the column permutation)
    const int jg = (n0 >> 6) + wc;          // 64-col group = 16 natural j's
    const int j = jg * 16 + l15;            // natural hidden index in [0,2048)
#pragma unroll
    for (int mi = 0; mi < 4; mi++) {
#pragma unroll
        for (int r = 0; r < 4; r++) {
            const int m = m0 + wr * 64 + mi * 16 + quad * 4 + r;
            const size_t zb = (size_t)m * N + jg * 64 + l15;
            const float zi = acc[mi][0][r] + Zx[zb];
            const float zf = acc[mi][1][r] + Zx[zb + 16];
            const float zg = acc[mi][2][r] + Zx[zb + 32];
            const float zo = acc[mi][3][r] + Zx[zb + 48];
            const float i_ = sigm(zi);
            const float f_ = sigm(zf);
            const float g_ = tanhx(zg);
            const float o_ = sigm(zo);
            const size_t cb = (size_t)m * 2048 + j;
            const float cn = f_ * c[cb] + i_ * g_;
            c[cb] = cn;
            hout[cb] = f2bf(o_ * tanhx(cn));
        }
    }
}

// ---- t=0 gates (h0=c0=0): z = Zx_0 (permuted layout) -> c, h ----
__global__ __launch_bounds__(256) void gate0(
    const float* __restrict__ Zx, float* __restrict__ c, u16* __restrict__ h)
{
    const int idx = blockIdx.x * 256 + threadIdx.x;   // 1024*512
    const int b = idx >> 9;
    const int j = (idx & 511) * 4;                    // 4 consecutive j, same 16-group
    const size_t base = (size_t)b * 8192 + ((j >> 4) << 6) + (j & 15);
    const float4 vi = *(const float4*)&Zx[base];
    const float4 vf = *(const float4*)&Zx[base + 16];
    const float4 vg = *(const float4*)&Zx[base + 32];
    const float4 vo = *(const float4*)&Zx[base + 48];
    float ia[4] = {vi.x, vi.y, vi.z, vi.w};
    float fa[4] = {vf.x, vf.y, vf.z, vf.w};
    float ga[4] = {vg.x, vg.y, vg.z, vg.w};
    float oa[4] = {vo.x, vo.y, vo.z, vo.w};
    float cn[4]; u16x4 hv;
#pragma unroll
    for (int q = 0; q < 4; q++) {
        (void)fa;
        const float i_ = sigm(ia[q]);
        const float g_ = tanhx(ga[q]);
        const float o_ = sigm(oa[q]);
        cn[q] = i_ * g_;                    // f * 0 = 0
        hv[q] = f2bf(o_ * tanhx(cn[q]));
        (void)sigm(fa[q]);
    }
    const size_t cb = (size_t)b * 2048 + j;
    *(float4*)&c[cb] = make_float4(cn[0], cn[1], cn[2], cn[3]);
    *(u16x4*)&h[cb] = hv;
}

// ---- MLP GEMM: 64x128 tile (256 blocks), relu(A@Bt^T + bias) -> bf16 ----
__global__ __launch_bounds__(256, 4) void gemm_mlp(
    const u16* __restrict__ A, const u16* __restrict__ Bt,
    const float* __restrict__ bias, u16* __restrict__ Cb, int K)
{
    const int N = 2048;
    __shared__ alignas(16) u16 sA[64 * 32];
    __shared__ alignas(16) u16 sB[128 * 32];
    const int t = threadIdx.x;
    const int lane = t & 63;
    const int w = t >> 6;
    const int wr = w >> 1, wc = w & 1;       // wave tile 32x64
    const int l15 = lane & 15, quad = lane >> 4;
    const int m0 = blockIdx.x * 64, n0 = blockIdx.y * 128;
    const int rA = t >> 2, cA = (t & 3) * 8;             // 256 A-chunks
    const int r1 = t >> 2, c1 = (t & 3) * 8;             // B chunks t, t+256
    const int r2 = (t + 256) >> 2, c2 = ((t + 256) & 3) * 8;

    floatx4 acc[2][4] = {};
    for (int k0 = 0; k0 < K; k0 += 32) {
        async16(A + (size_t)(m0 + rA) * K + k0 + cA, sA + t * 8);
        async16(Bt + (size_t)(n0 + r1) * K + k0 + c1, sB + t * 8);
        async16(Bt + (size_t)(n0 + r2) * K + k0 + c2, sB + (t + 256) * 8);
        __syncthreads();
        bf16x8 af[2], bfr[4];
#pragma unroll
        for (int mi = 0; mi < 2; mi++)
            af[mi] = *(const bf16x8*)&sA[(wr * 32 + mi * 16 + l15) * 32 + quad * 8];
#pragma unroll
        for (int ni = 0; ni < 4; ni++)
            bfr[ni] = *(const bf16x8*)&sB[(wc * 64 + ni * 16 + l15) * 32 + quad * 8];
#pragma unroll
        for (int mi = 0; mi < 2; mi++)
#pragma unroll
            for (int ni = 0; ni < 4; ni++)
                acc[mi][ni] = __builtin_amdgcn_mfma_f32_16x16x32_bf16(
                    af[mi], bfr[ni], acc[mi][ni], 0, 0, 0);
        __syncthreads();
    }
#pragma unroll
    for (int mi = 0; mi < 2; mi++) {
#pragma unroll
        for (int ni = 0; ni < 4; ni++) {
            const int n = n0 + wc * 64 + ni * 16 + l15;
            const float bv = bias[n];
#pragma unroll
            for (int r = 0; r < 4; r++) {
                const int m = m0 + wr * 32 + mi * 16 + quad * 4 + r;
                float x = acc[mi][ni][r] + bv;
                x = x > 0.f ? x : 0.f;
                Cb[(size_t)m * N + n] = f2bf(x);
            }
        }
    }
}

// ---- head: logits = a2 @ W3 + b3 (f32), softmax over 2, f32 out ----
__global__ __launch_bounds__(256) void head_kernel(
    const u16* __restrict__ a2, const float* __restrict__ W3,
    const float* __restrict__ b3, float* __restrict__ out)
{
    const int t = threadIdx.x;
    const int w = t >> 6, lane = t & 63;
    const int b = blockIdx.x * 4 + w;
    float s0 = 0.f, s1 = 0.f;
    for (int k = lane; k < 2048; k += 64) {
        unsigned int u = ((unsigned int)a2[(size_t)b * 2048 + k]) << 16;
        float a; __builtin_memcpy(&a, &u, 4);
        s0 += a * W3[2 * k];
        s1 += a * W3[2 * k + 1];
    }
#pragma unroll
    for (int off = 32; off > 0; off >>= 1) {
        s0 += __shfl_down(s0, off);
        s1 += __shfl_down(s1, off);
    }
    if (lane == 0) {
        const float l0 = s0 + b3[0];
        const float l1 = s1 + b3[1];
        const float m = fmaxf(l0, l1);
        const float e0 = __expf(l0 - m), e1 = __expf(l1 - m);
        const float inv = 1.f / (e0 + e1);
        out[2 * b]     = e0 * inv;
        out[2 * b + 1] = e1 * inv;
    }
}

extern "C" void kernel_launch(void* const* d_in, const int* in_sizes, int n_in,
                              void* d_out, int out_size, void* d_ws, size_t ws_size,
                              hipStream_t stream) {
    const int*   path = (const int*)d_in[0];
    const float* emb  = (const float*)d_in[1];
    const float* W    = (const float*)d_in[2];
    const float* U    = (const float*)d_in[3];
    const float* bl   = (const float*)d_in[4];
    const float* W1   = (const float*)d_in[5];
    const float* b1   = (const float*)d_in[6];
    const float* W2   = (const float*)d_in[7];
    const float* b2   = (const float*)d_in[8];
    const float* W3   = (const float*)d_in[9];
    const float* b3   = (const float*)d_in[10];

    // workspace layout (bytes)
    const size_t NEED = 297795584;
    if (ws_size < NEED) return;
    char* ws = (char*)d_ws;
    u16*   Wt  = (u16*)  (ws + 0);          // 8192x2048 bf16 perm (33554432)
    u16*   Ut  = (u16*)  (ws + 33554432);   // 8192x2048 bf16 perm
    u16*   W1t = (u16*)  (ws + 67108864);   // 2048x2048 bf16 (8388608)
    u16*   W2t = (u16*)  (ws + 75497472);
    u16*   X   = (u16*)  (ws + 83886080);   // 5120x2048 bf16 (20971520)
    float* Zx  = (float*)(ws + 104857600);  // 5120x8192 f32 (167772160)
    float* c   = (float*)(ws + 272629760);  // 1024x2048 f32 (8388608)
    u16*   hA  = (u16*)  (ws + 281018368);  // 1024x2048 bf16 (4194304)
    u16*   hB  = (u16*)  (ws + 285212672);
    u16*   a1  = (u16*)  (ws + 289406976);
    u16*   a2  = (u16*)  (ws + 293601280);

    transpose_f32_bf16<true ><<<dim3(128, 32), 256, 0, stream>>>(W, Wt, 2048, 8192);
    transpose_f32_bf16<true ><<<dim3(128, 32), 256, 0, stream>>>(U, Ut, 2048, 8192);
    transpose_f32_bf16<false><<<dim3(32, 32), 256, 0, stream>>>(W1, W1t, 2048, 2048);
    transpose_f32_bf16<false><<<dim3(32, 32), 256, 0, stream>>>(W2, W2t, 2048, 2048);
    gather_x<<<5120, 256, 0, stream>>>(path, emb, X);

    // all 5 timesteps' x@W in one GEMM (M=5120)
    gemm_zx<<<dim3(40, 64), 256, 0, stream>>>(X, Wt, bl, Zx, 5120, 8192, 2048);

    gate0<<<2048, 256, 0, stream>>>(Zx, c, hA);
    for (int t = 1; t < 5; t++) {
        const u16* hin = (t & 1) ? hA : hB;
        u16* hout      = (t & 1) ? hB : hA;
        gemm_step<<<dim3(8, 64), 256, 0, stream>>>(
            hin, Ut, Zx + (size_t)t * 1024 * 8192, c, hout);
    }
    // after t=4, latest h is in hA
    gemm_mlp<<<dim3(16, 16), 256, 0, stream>>>(hA, W1t, b1, a1, 2048);
    gemm_mlp<<<dim3(16, 16), 256, 0, stream>>>(a1, W2t, b2, a2, 2048);
    head_kernel<<<256, 256, 0, stream>>>(a2, W3, b3, (float*)d_out);
}

// Round 4
// 1113.799 us; speedup vs baseline: 1.1333x; 1.0144x over previous
//
#include <hip/hip_runtime.h>
#include <hip/hip_bf16.h>

typedef unsigned short u16;
typedef short bf16x8 __attribute__((ext_vector_type(8)));    // 8 bf16 = 4 VGPRs
typedef float floatx4 __attribute__((ext_vector_type(4)));
typedef unsigned short u16x4 __attribute__((ext_vector_type(4)));
typedef unsigned short u16x8 __attribute__((ext_vector_type(8)));

__device__ __forceinline__ u16 f2bf(float f) {
    unsigned int x; __builtin_memcpy(&x, &f, 4);
    unsigned int r = x + 0x7fffu + ((x >> 16) & 1u);   // RNE
    return (u16)(r >> 16);
}
__device__ __forceinline__ float sigm(float x) {
    return 1.f / (1.f + __expf(-x));
}
__device__ __forceinline__ float tanhx(float x) {
    x = fminf(fmaxf(x, -15.f), 15.f);
    float e = __expf(2.f * x);
    return (e - 1.f) / (e + 1.f);
}

// column permutation: original col c = gate*2048 + j (j = j_hi*16 + j_lo)
//   -> permuted c' = j_hi*64 + gate*16 + j_lo
// each 64-col group holds {i,f,g,o}x16 for 16 consecutive j -> in the GEMM
// epilogue, ni (16-col subtile index within a wave's 64 cols) IS the gate
// index and no cross-lane exchange is needed for the LSTM cell update.
__device__ __forceinline__ int permc(int c) {
    int gate = c >> 11, j = c & 2047;
    return ((j >> 4) << 6) | (gate << 4) | (j & 15);
}

// async 16B global->LDS (global_load_lds_dwordx4). LDS dest is wave-uniform
// base + lane*16 -> thread t must map to LDS chunk t (m97 pattern, no padding).
__device__ __forceinline__ void async16(const void* g, void* l) {
    __builtin_amdgcn_global_load_lds(
        (__attribute__((address_space(1))) void*)(void*)(g),
        (__attribute__((address_space(3))) void*)(l),
        16, 0, 0);
}

// ------- paired transpose+convert: (K,N) f32 -> (N,K) bf16, optional col-perm -------
template <bool PERM>
__global__ __launch_bounds__(256) void transpose2(
    const float* __restrict__ in0, const float* __restrict__ in1,
    u16* __restrict__ out0, u16* __restrict__ out1, int K, int N)
{
    const float* in = blockIdx.z ? in1 : in0;
    u16* out        = blockIdx.z ? out1 : out0;
    __shared__ float tile[64][65];
    const int n0 = blockIdx.x * 64, k0 = blockIdx.y * 64;
    const int t = threadIdx.x;
    const int tc = t & 15, tr = t >> 4;
#pragma unroll
    for (int i = 0; i < 4; i++) {
        int k = i * 16 + tr;
        int n = tc * 4;
        float4 v = *(const float4*)&in[(size_t)(k0 + k) * N + n0 + n];
        tile[k][n + 0] = v.x; tile[k][n + 1] = v.y;
        tile[k][n + 2] = v.z; tile[k][n + 3] = v.w;
    }
    __syncthreads();
#pragma unroll
    for (int i = 0; i < 4; i++) {
        int n = i * 16 + tr;
        int k = tc * 4;
        u16x4 v;
        v.x = f2bf(tile[k + 0][n]);
        v.y = f2bf(tile[k + 1][n]);
        v.z = f2bf(tile[k + 2][n]);
        v.w = f2bf(tile[k + 3][n]);
        const int row = PERM ? permc(n0 + n) : (n0 + n);
        *(u16x4*)&out[(size_t)row * K + k0 + k] = v;
    }
}

// ------ gather + convert: X[t][b] = [emb[path[b][1+2t]], emb[path[b][2+2t]]] f32->bf16 ------
__global__ __launch_bounds__(256) void gather_x(
    const int* __restrict__ path, const float* __restrict__ emb, u16* __restrict__ X)
{
    const int blk = blockIdx.x;          // t*1024 + b
    const int t = blk >> 10, b = blk & 1023;
    const int tt = threadIdx.x;
    const int half = tt >> 7;
    const int idx = path[b * 11 + 1 + 2 * t + half];
    const int j = (tt & 127) * 8;
    const float4 v0 = *(const float4*)&emb[(size_t)idx * 1024 + j];
    const float4 v1 = *(const float4*)&emb[(size_t)idx * 1024 + j + 4];
    u16x8 o;
    o[0] = f2bf(v0.x); o[1] = f2bf(v0.y); o[2] = f2bf(v0.z); o[3] = f2bf(v0.w);
    o[4] = f2bf(v1.x); o[5] = f2bf(v1.y); o[6] = f2bf(v1.z); o[7] = f2bf(v1.w);
    *(u16x8*)&X[(size_t)blk * 2048 + half * 1024 + j] = o;
}

// ---- batched Zx GEMM + fused t=0 gates ----
// Zx(5120x8192,perm) = X(5120x2048) @ Wt'^T; rows m<1024 (t=0) go straight
// through the LSTM cell (c0=h0=0) writing c and h0; rows m>=1024 write Zx+bias.
__global__ __launch_bounds__(256, 2) void gemm_zx(
    const u16* __restrict__ A, const u16* __restrict__ Bt,
    const float* __restrict__ bias, float* __restrict__ Zx,
    float* __restrict__ c, u16* __restrict__ h0)
{
    const int N = 8192, K = 2048;
    __shared__ alignas(16) u16 sA[128 * 32];
    __shared__ alignas(16) u16 sB[128 * 32];
    const int t = threadIdx.x;
    const int lane = t & 63;
    const int w = t >> 6;
    const int wr = w >> 1, wc = w & 1;
    const int l15 = lane & 15, quad = lane >> 4;
    // 4x4 super-tile swizzle for L2 locality (m supers: 10, n supers: 16)
    const int bid = blockIdx.x;
    const int g = bid >> 4, i = bid & 15;
    const int mb = (g % 10) * 4 + (i & 3);
    const int nb = (g / 10) * 4 + (i >> 2);
    const int m0 = mb * 128, n0 = nb * 128;
    const int ch1 = t, ch2 = t + 256;
    const int r1 = ch1 >> 2, c1 = (ch1 & 3) * 8;
    const int r2 = ch2 >> 2, c2 = (ch2 & 3) * 8;

    floatx4 acc[4][4] = {};
    for (int k0 = 0; k0 < K; k0 += 32) {
        async16(A + (size_t)(m0 + r1) * K + k0 + c1, sA + ch1 * 8);
        async16(A + (size_t)(m0 + r2) * K + k0 + c2, sA + ch2 * 8);
        async16(Bt + (size_t)(n0 + r1) * K + k0 + c1, sB + ch1 * 8);
        async16(Bt + (size_t)(n0 + r2) * K + k0 + c2, sB + ch2 * 8);
        __syncthreads();
        bf16x8 af[4], bfr[4];
#pragma unroll
        for (int mi = 0; mi < 4; mi++)
            af[mi] = *(const bf16x8*)&sA[(wr * 64 + mi * 16 + l15) * 32 + quad * 8];
#pragma unroll
        for (int ni = 0; ni < 4; ni++)
            bfr[ni] = *(const bf16x8*)&sB[(wc * 64 + ni * 16 + l15) * 32 + quad * 8];
#pragma unroll
        for (int mi = 0; mi < 4; mi++)
#pragma unroll
            for (int ni = 0; ni < 4; ni++)
                acc[mi][ni] = __builtin_amdgcn_mfma_f32_16x16x32_bf16(
                    af[mi], bfr[ni], acc[mi][ni], 0, 0, 0);
        __syncthreads();
    }

    if (m0 < 1024) {
        // t=0 LSTM cell fused: ni = gate, c0 = 0 so c = i*g
        const int jg = (n0 >> 6) + wc;
        const int j = jg * 16 + l15;
        const float bi = bias[j];
        const float bg = bias[4096 + j];
        const float bo = bias[6144 + j];
#pragma unroll
        for (int mi = 0; mi < 4; mi++) {
#pragma unroll
            for (int r = 0; r < 4; r++) {
                const int m = m0 + wr * 64 + mi * 16 + quad * 4 + r;
                const float i_ = sigm(acc[mi][0][r] + bi);
                const float g_ = tanhx(acc[mi][2][r] + bg);
                const float o_ = sigm(acc[mi][3][r] + bo);
                const float cn = i_ * g_;
                const size_t cb = (size_t)m * 2048 + j;
                c[cb] = cn;
                h0[cb] = f2bf(o_ * tanhx(cn));
            }
        }
    } else {
#pragma unroll
        for (int mi = 0; mi < 4; mi++) {
#pragma unroll
            for (int ni = 0; ni < 4; ni++) {
                const int n = n0 + wc * 64 + ni * 16 + l15;   // permuted col
                const float bv = bias[(((n >> 4) & 3) << 11) | ((n >> 6) << 4) | (n & 15)];
#pragma unroll
                for (int r = 0; r < 4; r++) {
                    const int m = m0 + wr * 64 + mi * 16 + quad * 4 + r;
                    Zx[(size_t)m * N + n] = acc[mi][ni][r] + bv;
                }
            }
        }
    }
}

// ---- fused step: z = Zx_t + h@Ut'(perm); gates in epilogue -> c (f32), hout (bf16) ----
// 64x128 tile, grid 1024 = 4 blocks/CU for the sequential phase.
__global__ __launch_bounds__(256, 4) void gemm_step(
    const u16* __restrict__ hin, const u16* __restrict__ Bt,
    const float* __restrict__ Zx, float* __restrict__ c, u16* __restrict__ hout)
{
    const int N = 8192, K = 2048;
    __shared__ alignas(16) u16 sA[64 * 32];
    __shared__ alignas(16) u16 sB[128 * 32];
    const int t = threadIdx.x;
    const int lane = t & 63;
    const int w = t >> 6;
    const int wr = w >> 1, wc = w & 1;       // wave tile 32x64
    const int l15 = lane & 15, quad = lane >> 4;
    // 4x4 super-tile swizzle (m supers: 4, n supers: 16)
    const int bid = blockIdx.x;
    const int g = bid >> 4, i = bid & 15;
    const int mb = (g & 3) * 4 + (i & 3);
    const int nb = (g >> 2) * 4 + (i >> 2);
    const int m0 = mb * 64, n0 = nb * 128;
    const int rA = t >> 2, cA = (t & 3) * 8;             // 256 A-chunks
    const int r1 = t >> 2, c1 = (t & 3) * 8;             // 512 B-chunks
    const int r2 = (t + 256) >> 2, c2 = ((t + 256) & 3) * 8;

    floatx4 acc[2][4] = {};
    for (int k0 = 0; k0 < K; k0 += 32) {
        async16(hin + (size_t)(m0 + rA) * K + k0 + cA, sA + t * 8);
        async16(Bt + (size_t)(n0 + r1) * K + k0 + c1, sB + t * 8);
        async16(Bt + (size_t)(n0 + r2) * K + k0 + c2, sB + (t + 256) * 8);
        __syncthreads();
        bf16x8 af[2], bfr[4];
#pragma unroll
        for (int mi = 0; mi < 2; mi++)
            af[mi] = *(const bf16x8*)&sA[(wr * 32 + mi * 16 + l15) * 32 + quad * 8];
#pragma unroll
        for (int ni = 0; ni < 4; ni++)
            bfr[ni] = *(const bf16x8*)&sB[(wc * 64 + ni * 16 + l15) * 32 + quad * 8];
#pragma unroll
        for (int mi = 0; mi < 2; mi++)
#pragma unroll
            for (int ni = 0; ni < 4; ni++)
                acc[mi][ni] = __builtin_amdgcn_mfma_f32_16x16x32_bf16(
                    af[mi], bfr[ni], acc[mi][ni], 0, 0, 0);
        __syncthreads();
    }

    // epilogue: ni = gate index (column permutation)
    const int jg = (n0 >> 6) + wc;          // 64-col group = 16 natural j's
    const int j = jg * 16 + l15;
#pragma unroll
    for (int mi = 0; mi < 2; mi++) {
#pragma unroll
        for (int r = 0; r < 4; r++) {
            const int m = m0 + wr * 32 + mi * 16 + quad * 4 + r;
            const size_t zb = (size_t)m * N + jg * 64 + l15;
            const float zi = acc[mi][0][r] + Zx[zb];
            const float zf = acc[mi][1][r] + Zx[zb + 16];
            const float zg = acc[mi][2][r] + Zx[zb + 32];
            const float zo = acc[mi][3][r] + Zx[zb + 48];
            const float i_ = sigm(zi);
            const float f_ = sigm(zf);
            const float g_ = tanhx(zg);
            const float o_ = sigm(zo);
            const size_t cb = (size_t)m * 2048 + j;
            const float cn = f_ * c[cb] + i_ * g_;
            c[cb] = cn;
            hout[cb] = f2bf(o_ * tanhx(cn));
        }
    }
}

// ---- MLP GEMM: 64x128 tile, relu(A@Bt^T + bias) -> bf16 ----
__global__ __launch_bounds__(256, 4) void gemm_mlp(
    const u16* __restrict__ A, const u16* __restrict__ Bt,
    const float* __restrict__ bias, u16* __restrict__ Cb, int K)
{
    const int N = 2048;
    __shared__ alignas(16) u16 sA[64 * 32];
    __shared__ alignas(16) u16 sB[128 * 32];
    const int t = threadIdx.x;
    const int lane = t & 63;
    const int w = t >> 6;
    const int wr = w >> 1, wc = w & 1;       // wave tile 32x64
    const int l15 = lane & 15, quad = lane >> 4;
    const int m0 = blockIdx.x * 64, n0 = blockIdx.y * 128;
    const int rA = t >> 2, cA = (t & 3) * 8;
    const int r1 = t >> 2, c1 = (t & 3) * 8;
    const int r2 = (t + 256) >> 2, c2 = ((t + 256) & 3) * 8;

    floatx4 acc[2][4] = {};
    for (int k0 = 0; k0 < K; k0 += 32) {
        async16(A + (size_t)(m0 + rA) * K + k0 + cA, sA + t * 8);
        async16(Bt + (size_t)(n0 + r1) * K + k0 + c1, sB + t * 8);
        async16(Bt + (size_t)(n0 + r2) * K + k0 + c2, sB + (t + 256) * 8);
        __syncthreads();
        bf16x8 af[2], bfr[4];
#pragma unroll
        for (int mi = 0; mi < 2; mi++)
            af[mi] = *(const bf16x8*)&sA[(wr * 32 + mi * 16 + l15) * 32 + quad * 8];
#pragma unroll
        for (int ni = 0; ni < 4; ni++)
            bfr[ni] = *(const bf16x8*)&sB[(wc * 64 + ni * 16 + l15) * 32 + quad * 8];
#pragma unroll
        for (int mi = 0; mi < 2; mi++)
#pragma unroll
            for (int ni = 0; ni < 4; ni++)
                acc[mi][ni] = __builtin_amdgcn_mfma_f32_16x16x32_bf16(
                    af[mi], bfr[ni], acc[mi][ni], 0, 0, 0);
        __syncthreads();
    }
#pragma unroll
    for (int mi = 0; mi < 2; mi++) {
#pragma unroll
        for (int ni = 0; ni < 4; ni++) {
            const int n = n0 + wc * 64 + ni * 16 + l15;
            const float bv = bias[n];
#pragma unroll
            for (int r = 0; r < 4; r++) {
                const int m = m0 + wr * 32 + mi * 16 + quad * 4 + r;
                float x = acc[mi][ni][r] + bv;
                x = x > 0.f ? x : 0.f;
                Cb[(size_t)m * N + n] = f2bf(x);
            }
        }
    }
}

// ---- head: logits = a2 @ W3 + b3 (f32), softmax over 2, f32 out ----
__global__ __launch_bounds__(256) void head_kernel(
    const u16* __restrict__ a2, const float* __restrict__ W3,
    const float* __restrict__ b3, float* __restrict__ out)
{
    const int t = threadIdx.x;
    const int w = t >> 6, lane = t & 63;
    const int b = blockIdx.x * 4 + w;
    float s0 = 0.f, s1 = 0.f;
    for (int k = lane; k < 2048; k += 64) {
        unsigned int u = ((unsigned int)a2[(size_t)b * 2048 + k]) << 16;
        float a; __builtin_memcpy(&a, &u, 4);
        s0 += a * W3[2 * k];
        s1 += a * W3[2 * k + 1];
    }
#pragma unroll
    for (int off = 32; off > 0; off >>= 1) {
        s0 += __shfl_down(s0, off);
        s1 += __shfl_down(s1, off);
    }
    if (lane == 0) {
        const float l0 = s0 + b3[0];
        const float l1 = s1 + b3[1];
        const float m = fmaxf(l0, l1);
        const float e0 = __expf(l0 - m), e1 = __expf(l1 - m);
        const float inv = 1.f / (e0 + e1);
        out[2 * b]     = e0 * inv;
        out[2 * b + 1] = e1 * inv;
    }
}

extern "C" void kernel_launch(void* const* d_in, const int* in_sizes, int n_in,
                              void* d_out, int out_size, void* d_ws, size_t ws_size,
                              hipStream_t stream) {
    const int*   path = (const int*)d_in[0];
    const float* emb  = (const float*)d_in[1];
    const float* W    = (const float*)d_in[2];
    const float* U    = (const float*)d_in[3];
    const float* bl   = (const float*)d_in[4];
    const float* W1   = (const float*)d_in[5];
    const float* b1   = (const float*)d_in[6];
    const float* W2   = (const float*)d_in[7];
    const float* b2   = (const float*)d_in[8];
    const float* W3   = (const float*)d_in[9];
    const float* b3   = (const float*)d_in[10];

    // workspace layout (bytes)
    const size_t NEED = 297795584;
    if (ws_size < NEED) return;
    char* ws = (char*)d_ws;
    u16*   Wt  = (u16*)  (ws + 0);          // 8192x2048 bf16 perm (33554432)
    u16*   Ut  = (u16*)  (ws + 33554432);   // 8192x2048 bf16 perm
    u16*   W1t = (u16*)  (ws + 67108864);   // 2048x2048 bf16 (8388608)
    u16*   W2t = (u16*)  (ws + 75497472);
    u16*   X   = (u16*)  (ws + 83886080);   // 5120x2048 bf16 (20971520)
    float* Zx  = (float*)(ws + 104857600);  // 5120x8192 f32 (167772160; t=0 region unused)
    float* c   = (float*)(ws + 272629760);  // 1024x2048 f32 (8388608)
    u16*   hA  = (u16*)  (ws + 281018368);  // 1024x2048 bf16 (4194304)
    u16*   hB  = (u16*)  (ws + 285212672);
    u16*   a1  = (u16*)  (ws + 289406976);
    u16*   a2  = (u16*)  (ws + 293601280);

    transpose2<true ><<<dim3(128, 32, 2), 256, 0, stream>>>(W, U, Wt, Ut, 2048, 8192);
    transpose2<false><<<dim3(32, 32, 2), 256, 0, stream>>>(W1, W2, W1t, W2t, 2048, 2048);
    gather_x<<<5120, 256, 0, stream>>>(path, emb, X);

    // all 5 timesteps' x@W in one GEMM; t=0 rows run the LSTM cell in-epilogue
    gemm_zx<<<2560, 256, 0, stream>>>(X, Wt, bl, Zx, c, hA);

    for (int t = 1; t < 5; t++) {
        const u16* hin = (t & 1) ? hA : hB;
        u16* hout      = (t & 1) ? hB : hA;
        gemm_step<<<1024, 256, 0, stream>>>(
            hin, Ut, Zx + (size_t)t * 1024 * 8192, c, hout);
    }
    // after t=4, latest h is in hA
    gemm_mlp<<<dim3(16, 16), 256, 0, stream>>>(hA, W1t, b1, a1, 2048);
    gemm_mlp<<<dim3(16, 16), 256, 0, stream>>>(a1, W2t, b2, a2, 2048);
    head_kernel<<<256, 256, 0, stream>>>(a2, W3, b3, (float*)d_out);
}